// Round 1
// baseline (1560.103 us; speedup 1.0000x reference)
//
#include <hip/hip_runtime.h>

typedef _Float16 half2_t __attribute__((ext_vector_type(2)));
typedef unsigned int u32;

#define NW 252   // total windows: 1 initial + 3 warmup + 248 autoregressive

__device__ inline u32 pk(float x, float y) {
  half2_t h; h.x = (_Float16)x; h.y = (_Float16)y;
  return __builtin_bit_cast(u32, h);
}

__device__ inline float fdot2(u32 a, u32 b, float c) {
#if __has_builtin(__builtin_amdgcn_fdot2)
  return __builtin_amdgcn_fdot2(__builtin_bit_cast(half2_t, a),
                                __builtin_bit_cast(half2_t, b), c, false);
#else
  half2_t ah = __builtin_bit_cast(half2_t, a);
  half2_t bh = __builtin_bit_cast(half2_t, b);
  return c + (float)ah.x * (float)bh.x + (float)ah.y * (float)bh.y;
#endif
}

__device__ inline float fast_rcp(float x) {
#if __has_builtin(__builtin_amdgcn_rcpf)
  return __builtin_amdgcn_rcpf(x);
#else
  return 1.0f / x;
#endif
}

__device__ inline float sigf(float x)  { return fast_rcp(1.0f + __expf(-x)); }
__device__ inline float tanh_(float x) { return 1.0f - 2.0f * fast_rcp(__expf(2.0f * x) + 1.0f); }

// butterfly sum over the 4 lanes of a quad (ks = tid&3) via DPP quad_perm (VALU pipe)
__device__ inline float quad_reduce(float v) {
  int x = __builtin_bit_cast(int, v);
  int y = __builtin_amdgcn_update_dpp(0, x, 0xB1, 0xF, 0xF, true); // [1,0,3,2] xor1
  v += __builtin_bit_cast(float, y);
  x = __builtin_bit_cast(int, v);
  y = __builtin_amdgcn_update_dpp(0, x, 0x4E, 0xF, 0xF, true);     // [2,3,0,1] xor2
  v += __builtin_bit_cast(float, y);
  return v;
}

#define LOAD_SLICE(dst, basehalf)                                          \
  { const uint4* _p = (const uint4*)(basehalf) + ks * 4;                   \
    uint4 _q0 = _p[0], _q1 = _p[1], _q2 = _p[2], _q3 = _p[3];              \
    dst[0]=_q0.x;  dst[1]=_q0.y;  dst[2]=_q0.z;  dst[3]=_q0.w;             \
    dst[4]=_q1.x;  dst[5]=_q1.y;  dst[6]=_q1.z;  dst[7]=_q1.w;             \
    dst[8]=_q2.x;  dst[9]=_q2.y;  dst[10]=_q2.z; dst[11]=_q2.w;            \
    dst[12]=_q3.x; dst[13]=_q3.y; dst[14]=_q3.z; dst[15]=_q3.w; }

__global__ __launch_bounds__(512) void lstm_roll(
    const float* __restrict__ traj,
    const float* __restrict__ Wih0, const float* __restrict__ Whh0,
    const float* __restrict__ bih0, const float* __restrict__ bhh0,
    const float* __restrict__ Wih1, const float* __restrict__ Whh1,
    const float* __restrict__ bih1, const float* __restrict__ bhh1,
    const float* __restrict__ Wl,   const float* __restrict__ bl,
    float* __restrict__ out)
{
  const int b   = blockIdx.x;
  const int B   = gridDim.x;
  const int tid = threadIdx.x;
  const int j   = tid >> 2;   // hidden index 0..127
  const int ks  = tid & 3;    // k-slice 0..3 (32 k's each)

  __shared__ __align__(16) _Float16 h0buf[2][128];
  __shared__ __align__(16) _Float16 h1buf[2][128];
  __shared__ float sh_h1f[128];
  __shared__ float sh_Wl[256];
  __shared__ float trajS[256 * 3];
  __shared__ float preds[NW * 2];

  for (int i = tid; i < 768; i += 512) trajS[i] = traj[b * 768 + i];
  if (tid < 256) sh_Wl[tid] = Wl[tid];
  float blv = 0.0f;
  if (tid < 128) blv = bl[tid >> 6];

  // ---- register-resident weights: 4 gate rows x 32-k slice, f16 packed ----
  u32 wA[64], wB[64], wC[64];           // Whh0, Wih1, Whh1
  float b0r[4], b1r[4], w0r[12];
#pragma unroll
  for (int g = 0; g < 4; ++g) {
    const int row = g * 128 + j;
    b0r[g] = bih0[row] + bhh0[row];
    b1r[g] = bih1[row] + bhh1[row];
    w0r[g*3+0] = Wih0[row*3+0];
    w0r[g*3+1] = Wih0[row*3+1];
    w0r[g*3+2] = Wih0[row*3+2];
    const float4* pA = (const float4*)(Whh0 + row * 128 + ks * 32);
    const float4* pB = (const float4*)(Wih1 + row * 128 + ks * 32);
    const float4* pC = (const float4*)(Whh1 + row * 128 + ks * 32);
#pragma unroll
    for (int q = 0; q < 8; ++q) {
      float4 fa = pA[q], fb = pB[q], fc = pC[q];
      wA[g*16 + q*2    ] = pk(fa.x, fa.y);
      wA[g*16 + q*2 + 1] = pk(fa.z, fa.w);
      wB[g*16 + q*2    ] = pk(fb.x, fb.y);
      wB[g*16 + q*2 + 1] = pk(fb.z, fb.w);
      wC[g*16 + q*2    ] = pk(fc.x, fc.y);
      wC[g*16 + q*2 + 1] = pk(fc.z, fc.w);
    }
  }

  float c0 = 0.f, c1 = 0.f, h0f = 0.f, h1f = 0.f;
  __syncthreads();

#pragma unroll 1
  for (int w = 0; w < NW; ++w) {
    c0 = 0.f; c1 = 0.f;
    for (int t = 0; t < 4; ++t) {
      // ---- window input row t (features per phase) ----
      float x0, x1, x2;
      if (w < 4) {
        if (w == 0 || t < 3) {
          const float* r = &trajS[(w + t) * 3];
          x0 = r[0]; x1 = r[1]; x2 = r[2];
        } else {                       // warmup last row: [ctrl, p_{w-1}]
          x0 = trajS[(4 + w) * 3];
          x1 = preds[(w - 1) * 2];
          x2 = preds[(w - 1) * 2 + 1];
        }
      } else {                         // AR: [p0, p1, ctrl]
        const int s = w - 4;
        x0 = preds[(s + t) * 2];
        x1 = preds[(s + t) * 2 + 1];
        x2 = trajS[(4 + s + t) * 3];
      }
      const int rp = t & 1, wp = rp ^ 1;
      const bool lead = (ks == 0);

      // ================= layer 0 =================
      float acc0, acc1, acc2, acc3;
      {
        float a0 = b0r[0] + w0r[0]*x0 + w0r[1] *x1 + w0r[2] *x2;
        float a1 = b0r[1] + w0r[3]*x0 + w0r[4] *x1 + w0r[5] *x2;
        float a2 = b0r[2] + w0r[6]*x0 + w0r[7] *x1 + w0r[8] *x2;
        float a3 = b0r[3] + w0r[9]*x0 + w0r[10]*x1 + w0r[11]*x2;
        acc0 = lead ? a0 : 0.f;  acc1 = lead ? a1 : 0.f;
        acc2 = lead ? a2 : 0.f;  acc3 = lead ? a3 : 0.f;
      }
      if (t > 0) {
        u32 su[16];
        LOAD_SLICE(su, h0buf[rp]);
#pragma unroll
        for (int kk = 0; kk < 16; ++kk) {
          acc0 = fdot2(wA[     kk], su[kk], acc0);
          acc1 = fdot2(wA[16 + kk], su[kk], acc1);
          acc2 = fdot2(wA[32 + kk], su[kk], acc2);
          acc3 = fdot2(wA[48 + kk], su[kk], acc3);
        }
      }
      acc0 = quad_reduce(acc0); acc1 = quad_reduce(acc1);
      acc2 = quad_reduce(acc2); acc3 = quad_reduce(acc3);
      {
        float ig = sigf(acc0), fg = sigf(acc1), gg = tanh_(acc2), og = sigf(acc3);
        c0  = fg * c0 + ig * gg;
        h0f = og * tanh_(c0);
      }
      if (lead) h0buf[wp][j] = (_Float16)h0f;
      __syncthreads();

      // ================= layer 1 =================
      acc0 = lead ? b1r[0] : 0.f;  acc1 = lead ? b1r[1] : 0.f;
      acc2 = lead ? b1r[2] : 0.f;  acc3 = lead ? b1r[3] : 0.f;
      {
        u32 sy[16];
        LOAD_SLICE(sy, h0buf[wp]);          // y0[t] = h0 just written
#pragma unroll
        for (int kk = 0; kk < 16; ++kk) {
          acc0 = fdot2(wB[     kk], sy[kk], acc0);
          acc1 = fdot2(wB[16 + kk], sy[kk], acc1);
          acc2 = fdot2(wB[32 + kk], sy[kk], acc2);
          acc3 = fdot2(wB[48 + kk], sy[kk], acc3);
        }
      }
      if (t > 0) {
        u32 sh[16];
        LOAD_SLICE(sh, h1buf[rp]);
#pragma unroll
        for (int kk = 0; kk < 16; ++kk) {
          acc0 = fdot2(wC[     kk], sh[kk], acc0);
          acc1 = fdot2(wC[16 + kk], sh[kk], acc1);
          acc2 = fdot2(wC[32 + kk], sh[kk], acc2);
          acc3 = fdot2(wC[48 + kk], sh[kk], acc3);
        }
      }
      acc0 = quad_reduce(acc0); acc1 = quad_reduce(acc1);
      acc2 = quad_reduce(acc2); acc3 = quad_reduce(acc3);
      {
        float ig = sigf(acc0), fg = sigf(acc1), gg = tanh_(acc2), og = sigf(acc3);
        c1  = fg * c1 + ig * gg;
        h1f = og * tanh_(c1);
      }
      if (lead) {
        h1buf[wp][j] = (_Float16)h1f;
        if (t == 3) sh_h1f[j] = h1f;      // f32 copy for the head
      }
      if (t == 3) __syncthreads();
    }

    // ================= linear head + prediction =================
    if (tid < 128) {
      const int d = tid >> 6, l = tid & 63;
      float p = sh_Wl[d*128 + 2*l] * sh_h1f[2*l] + sh_Wl[d*128 + 2*l + 1] * sh_h1f[2*l + 1];
      p += __shfl_xor(p, 1);  p += __shfl_xor(p, 2);  p += __shfl_xor(p, 4);
      p += __shfl_xor(p, 8);  p += __shfl_xor(p, 16); p += __shfl_xor(p, 32);
      if (l == 0) {
        float base = (w < 4) ? trajS[(3 + w) * 3 + 1 + d] : preds[(w - 1) * 2 + d];
        preds[w * 2 + d] = base + p + blv;
      }
    }
    __syncthreads();
  }

  // ================= outputs =================
  // out: [B, 252, 2] predictions
  for (int i = tid; i < NW * 2; i += 512) out[b * (NW * 2) + i] = preds[i];
  // h_n: [2, B, 128], c_n: [2, B, 128]
  if (ks == 0) {
    const int oh = B * NW * 2;
    const int oc = oh + 2 * B * 128;
    out[oh +            b * 128 + j] = h0f;
    out[oh + B * 128 +  b * 128 + j] = h1f;
    out[oc +            b * 128 + j] = c0;
    out[oc + B * 128 +  b * 128 + j] = c1;
  }
}

extern "C" void kernel_launch(void* const* d_in, const int* in_sizes, int n_in,
                              void* d_out, int out_size, void* d_ws, size_t ws_size,
                              hipStream_t stream) {
  const float* traj = (const float*)d_in[0];
  const float* Wih0 = (const float*)d_in[1];
  const float* Whh0 = (const float*)d_in[2];
  const float* bih0 = (const float*)d_in[3];
  const float* bhh0 = (const float*)d_in[4];
  const float* Wih1 = (const float*)d_in[5];
  const float* Whh1 = (const float*)d_in[6];
  const float* bih1 = (const float*)d_in[7];
  const float* bhh1 = (const float*)d_in[8];
  const float* Wl   = (const float*)d_in[9];
  const float* bl   = (const float*)d_in[10];

  const int B = in_sizes[0] / (256 * 3);   // 128
  hipLaunchKernelGGL(lstm_roll, dim3(B), dim3(512), 0, stream,
                     traj, Wih0, Whh0, bih0, bhh0, Wih1, Whh1, bih1, bhh1,
                     Wl, bl, (float*)d_out);
}

// Round 2
// 1327.529 us; speedup vs baseline: 1.1752x; 1.1752x over previous
//
#include <hip/hip_runtime.h>

typedef _Float16 half2_t __attribute__((ext_vector_type(2)));
typedef unsigned int u32;

#define NW 252   // total windows: 1 initial + 3 warmup + 248 autoregressive

__device__ inline u32 pk(float x, float y) {
  half2_t h; h.x = (_Float16)x; h.y = (_Float16)y;
  return __builtin_bit_cast(u32, h);
}

__device__ inline float fdot2(u32 a, u32 b, float c) {
#if __has_builtin(__builtin_amdgcn_fdot2)
  return __builtin_amdgcn_fdot2(__builtin_bit_cast(half2_t, a),
                                __builtin_bit_cast(half2_t, b), c, false);
#else
  half2_t ah = __builtin_bit_cast(half2_t, a);
  half2_t bh = __builtin_bit_cast(half2_t, b);
  return c + (float)ah.x * (float)bh.x + (float)ah.y * (float)bh.y;
#endif
}

__device__ inline float fast_rcp(float x) {
#if __has_builtin(__builtin_amdgcn_rcpf)
  return __builtin_amdgcn_rcpf(x);
#else
  return 1.0f / x;
#endif
}

__device__ inline float sigf(float x)  { return fast_rcp(1.0f + __expf(-x)); }
__device__ inline float tanh_(float x) { return 1.0f - 2.0f * fast_rcp(__expf(2.0f * x) + 1.0f); }

// butterfly sum over the 4 lanes of a quad (ks = tid&3) via DPP quad_perm (VALU pipe)
__device__ inline float quad_reduce(float v) {
  int x = __builtin_bit_cast(int, v);
  int y = __builtin_amdgcn_update_dpp(0, x, 0xB1, 0xF, 0xF, true); // [1,0,3,2] xor1
  v += __builtin_bit_cast(float, y);
  x = __builtin_bit_cast(int, v);
  y = __builtin_amdgcn_update_dpp(0, x, 0x4E, 0xF, 0xF, true);     // [2,3,0,1] xor2
  v += __builtin_bit_cast(float, y);
  return v;
}

#define LOAD_SLICE(dst, basehalf)                                          \
  { const uint4* _p = (const uint4*)(basehalf) + ks * 4;                   \
    uint4 _q0 = _p[0], _q1 = _p[1], _q2 = _p[2], _q3 = _p[3];              \
    dst[0]=_q0.x;  dst[1]=_q0.y;  dst[2]=_q0.z;  dst[3]=_q0.w;             \
    dst[4]=_q1.x;  dst[5]=_q1.y;  dst[6]=_q1.z;  dst[7]=_q1.w;             \
    dst[8]=_q2.x;  dst[9]=_q2.y;  dst[10]=_q2.z; dst[11]=_q2.w;            \
    dst[12]=_q3.x; dst[13]=_q3.y; dst[14]=_q3.z; dst[15]=_q3.w; }

// __launch_bounds__(512, 2): 2 waves/EU floor -> 256 arch-VGPR budget so the
// 192 packed-weight regs stay directly addressable (R1 showed VGPR_Count=128).
__global__ __launch_bounds__(512, 2) void lstm_roll(
    const float* __restrict__ traj,
    const float* __restrict__ Wih0, const float* __restrict__ Whh0,
    const float* __restrict__ bih0, const float* __restrict__ bhh0,
    const float* __restrict__ Wih1, const float* __restrict__ Whh1,
    const float* __restrict__ bih1, const float* __restrict__ bhh1,
    const float* __restrict__ Wl,   const float* __restrict__ bl,
    float* __restrict__ out)
{
  const int b   = blockIdx.x;
  const int B   = gridDim.x;
  const int tid = threadIdx.x;
  const int j   = tid >> 2;   // hidden index 0..127
  const int ks  = tid & 3;    // k-slice 0..3 (32 k's each)

  __shared__ __align__(16) _Float16 h0buf[2][128];  // parity ping-pong
  __shared__ __align__(16) _Float16 h1buf[2][128];
  __shared__ float sh_h1f[128];      // f32 h1[3] for the head
  __shared__ float sh_Wl[256];
  __shared__ float trajS[256 * 3];
  __shared__ float preds[NW * 2];

  for (int i = tid; i < 768; i += 512) trajS[i] = traj[b * 768 + i];
  if (tid < 256) sh_Wl[tid] = Wl[tid];
  float blv = 0.0f;
  if (tid < 8) blv = bl[tid >> 2];

  // ---- register-resident weights: 4 gate rows x 32-k slice, f16 packed ----
  u32 wA[64], wB[64], wC[64];           // Whh0, Wih1, Whh1
  float b0r[4], b1r[4], w0r[12];
#pragma unroll
  for (int g = 0; g < 4; ++g) {
    const int row = g * 128 + j;
    b0r[g] = bih0[row] + bhh0[row];
    b1r[g] = bih1[row] + bhh1[row];
    w0r[g*3+0] = Wih0[row*3+0];
    w0r[g*3+1] = Wih0[row*3+1];
    w0r[g*3+2] = Wih0[row*3+2];
    const float4* pA = (const float4*)(Whh0 + row * 128 + ks * 32);
    const float4* pB = (const float4*)(Wih1 + row * 128 + ks * 32);
    const float4* pC = (const float4*)(Whh1 + row * 128 + ks * 32);
#pragma unroll
    for (int q = 0; q < 8; ++q) {
      float4 fa = pA[q], fb = pB[q], fc = pC[q];
      wA[g*16 + q*2    ] = pk(fa.x, fa.y);
      wA[g*16 + q*2 + 1] = pk(fa.z, fa.w);
      wB[g*16 + q*2    ] = pk(fb.x, fb.y);
      wB[g*16 + q*2 + 1] = pk(fb.z, fb.w);
      wC[g*16 + q*2    ] = pk(fc.x, fc.y);
      wC[g*16 + q*2 + 1] = pk(fc.z, fc.w);
    }
  }

  float c0 = 0.f, c1 = 0.f, h0f = 0.f, h1f = 0.f;

  // ---- pipeline steps (every step reads parity p, writes parity p^1) ----
  auto L0STEP = [&](int w_, int t_, int p_) {
    float x0, x1, x2;
    if (w_ < 4) {
      if (w_ == 0 || t_ < 3) {
        const float* r = &trajS[(w_ + t_) * 3];
        x0 = r[0]; x1 = r[1]; x2 = r[2];
      } else {                       // warmup last row: [ctrl, p_{w-1}]
        x0 = trajS[(4 + w_) * 3];
        x1 = preds[(w_ - 1) * 2];
        x2 = preds[(w_ - 1) * 2 + 1];
      }
    } else {                         // AR: [p0, p1, ctrl]
      const int s_ = w_ - 4;
      x0 = preds[(s_ + t_) * 2];
      x1 = preds[(s_ + t_) * 2 + 1];
      x2 = trajS[(w_ + t_) * 3];
    }
    const bool lead = (ks == 0);
    float a0 = b0r[0] + w0r[0]*x0 + w0r[1] *x1 + w0r[2] *x2;
    float a1 = b0r[1] + w0r[3]*x0 + w0r[4] *x1 + w0r[5] *x2;
    float a2 = b0r[2] + w0r[6]*x0 + w0r[7] *x1 + w0r[8] *x2;
    float a3 = b0r[3] + w0r[9]*x0 + w0r[10]*x1 + w0r[11]*x2;
    float acc0 = lead ? a0 : 0.f, acc1 = lead ? a1 : 0.f;
    float acc2 = lead ? a2 : 0.f, acc3 = lead ? a3 : 0.f;
    if (t_ > 0) {
      u32 su[16];
      LOAD_SLICE(su, h0buf[p_]);
#pragma unroll
      for (int kk = 0; kk < 16; ++kk) {
        acc0 = fdot2(wA[     kk], su[kk], acc0);
        acc1 = fdot2(wA[16 + kk], su[kk], acc1);
        acc2 = fdot2(wA[32 + kk], su[kk], acc2);
        acc3 = fdot2(wA[48 + kk], su[kk], acc3);
      }
    }
    acc0 = quad_reduce(acc0); acc1 = quad_reduce(acc1);
    acc2 = quad_reduce(acc2); acc3 = quad_reduce(acc3);
    float ig = sigf(acc0), fg = sigf(acc1), gg = tanh_(acc2), og = sigf(acc3);
    float cp = t_ ? c0 : 0.f;
    c0  = fg * cp + ig * gg;
    h0f = og * tanh_(c0);
    if (lead) h0buf[p_ ^ 1][j] = (_Float16)h0f;
  };

  auto L1STEP = [&](int t_, int p_) {
    const bool lead = (ks == 0);
    float acc0 = lead ? b1r[0] : 0.f, acc1 = lead ? b1r[1] : 0.f;
    float acc2 = lead ? b1r[2] : 0.f, acc3 = lead ? b1r[3] : 0.f;
    {
      u32 sy[16];
      LOAD_SLICE(sy, h0buf[p_]);          // y0[t] = h0[t] (written last segment)
#pragma unroll
      for (int kk = 0; kk < 16; ++kk) {
        acc0 = fdot2(wB[     kk], sy[kk], acc0);
        acc1 = fdot2(wB[16 + kk], sy[kk], acc1);
        acc2 = fdot2(wB[32 + kk], sy[kk], acc2);
        acc3 = fdot2(wB[48 + kk], sy[kk], acc3);
      }
    }
    if (t_ > 0) {
      u32 sh[16];
      LOAD_SLICE(sh, h1buf[p_]);
#pragma unroll
      for (int kk = 0; kk < 16; ++kk) {
        acc0 = fdot2(wC[     kk], sh[kk], acc0);
        acc1 = fdot2(wC[16 + kk], sh[kk], acc1);
        acc2 = fdot2(wC[32 + kk], sh[kk], acc2);
        acc3 = fdot2(wC[48 + kk], sh[kk], acc3);
      }
    }
    acc0 = quad_reduce(acc0); acc1 = quad_reduce(acc1);
    acc2 = quad_reduce(acc2); acc3 = quad_reduce(acc3);
    float ig = sigf(acc0), fg = sigf(acc1), gg = tanh_(acc2), og = sigf(acc3);
    float cp = t_ ? c1 : 0.f;
    c1  = fg * cp + ig * gg;
    h1f = og * tanh_(c1);
    if (lead) {
      h1buf[p_ ^ 1][j] = (_Float16)h1f;
      if (t_ == 3) sh_h1f[j] = h1f;     // f32 copy for the head (read next segment)
    }
  };

  auto HD = [&](int w_) {               // head for window w_, 8 lanes, f32
    if (tid < 8) {
      const int d = tid >> 2;           // ks = tid&3 splits K
      const float* wrow = &sh_Wl[d * 128 + ks * 32];
      const float* hrow = &sh_h1f[ks * 32];
      float s = 0.f;
#pragma unroll
      for (int m = 0; m < 32; ++m) s = fmaf(wrow[m], hrow[m], s);
      s = quad_reduce(s);
      if (ks == 0) {
        float base = (w_ < 4) ? trajS[(3 + w_) * 3 + 1 + d] : preds[(w_ - 1) * 2 + d];
        preds[w_ * 2 + d] = base + s + blv;
      }
    }
  };

  __syncthreads();

  int p = 0;
  // prologue: L0[0] of window 0 (no h-dependency)
  L0STEP(0, 0, p);
  __syncthreads(); p ^= 1;

#pragma unroll 1
  for (int w = 0; w < NW; ++w) {
    // s0: head(w-1) || L0[1](w) || L1[0](w)
    if (w > 0) HD(w - 1);
    L0STEP(w, 1, p);
    L1STEP(0, p);
    __syncthreads(); p ^= 1;
    // s1: L0[2](w) || L1[1](w)
    L0STEP(w, 2, p);
    L1STEP(1, p);
    __syncthreads(); p ^= 1;
    // s2: L0[3](w) || L1[2](w)   (preds[w-1] ready since s0)
    L0STEP(w, 3, p);
    L1STEP(2, p);
    __syncthreads(); p ^= 1;
    // s3: L1[3](w) || L0[0](w+1)
    L1STEP(3, p);
    if (w < NW - 1) L0STEP(w + 1, 0, p);
    __syncthreads(); p ^= 1;
  }

  // epilogue: head of the last window
  HD(NW - 1);
  __syncthreads();

  // ================= outputs =================
  for (int i = tid; i < NW * 2; i += 512) out[b * (NW * 2) + i] = preds[i];
  if (ks == 0) {
    const int oh = B * NW * 2;
    const int oc = oh + 2 * B * 128;
    out[oh +            b * 128 + j] = h0f;
    out[oh + B * 128 +  b * 128 + j] = h1f;
    out[oc +            b * 128 + j] = c0;
    out[oc + B * 128 +  b * 128 + j] = c1;
  }
}

extern "C" void kernel_launch(void* const* d_in, const int* in_sizes, int n_in,
                              void* d_out, int out_size, void* d_ws, size_t ws_size,
                              hipStream_t stream) {
  const float* traj = (const float*)d_in[0];
  const float* Wih0 = (const float*)d_in[1];
  const float* Whh0 = (const float*)d_in[2];
  const float* bih0 = (const float*)d_in[3];
  const float* bhh0 = (const float*)d_in[4];
  const float* Wih1 = (const float*)d_in[5];
  const float* Whh1 = (const float*)d_in[6];
  const float* bih1 = (const float*)d_in[7];
  const float* bhh1 = (const float*)d_in[8];
  const float* Wl   = (const float*)d_in[9];
  const float* bl   = (const float*)d_in[10];

  const int B = in_sizes[0] / (256 * 3);   // 128
  hipLaunchKernelGGL(lstm_roll, dim3(B), dim3(512), 0, stream,
                     traj, Wih0, Whh0, bih0, bhh0, Wih1, Whh1, bih1, bhh1,
                     Wl, bl, (float*)d_out);
}